// Round 17
// baseline (343.933 us; speedup 1.0000x reference)
//
#include <hip/hip_runtime.h>
#include <math.h>

// StrategistGNN forward on MI355X. Round 17: edge-head staging via
// global_load_lds (direct-to-LDS DMA, no VGPR round trip, loads stay in
// flight until the barrier). N=4096, E=65536, H=128, 4x32 heads, L=4.

#define NN 4096
#define EE 65536
#define HH 128
#define NHEADS 4
#define HDIM 32
#define NLAYERS 4
#define NFEAT 16
#define GFEAT 8
#define EFEAT 4
#define KS 4     // key-splits for global attention
#define KPAD 296 // padded K stride (bf16) for edge-head GEMM
#define XSTR 136 // LDS row stride (bf16): 2-way bank aliasing only (free)
#define KSTR 40  // flash K-tile LDS row stride
#define VSTR 136 // flash V-tile LDS row stride (128 keys + 8 pad)
#define WPB 4541 // wprep blocks (ceil(1162497/256))

typedef short bf16x8 __attribute__((ext_vector_type(8)));
typedef float f32x4  __attribute__((ext_vector_type(4)));
union UB { uint4 u; bf16x8 v; };

__device__ __forceinline__ float gelu_f(float x){
  return 0.5f * x * (1.0f + erff(x * 0.7071067811865475f));
}
__device__ __forceinline__ float gelu_fast(float x){
  float u = x + 0.044715f * x * x * x;
  float t = __expf(-1.5957691216f * u);
  return x / (1.0f + t);
}
__device__ __forceinline__ float sigm_fast(float x){ return 1.0f / (1.0f + __expf(-x)); }
__device__ __forceinline__ float tanh_fast(float x){
  float t = __expf(-2.0f * fmaxf(x, -40.0f));
  return 1.0f - 2.0f * t / (1.0f + t);
}
__device__ __forceinline__ float softplus_f(float x){ return x > 20.0f ? x : log1pf(expf(x)); }
__device__ __forceinline__ unsigned short f2bf(float x){
  unsigned u = __float_as_uint(x);
  unsigned r = (u + 0x7FFFu + ((u >> 16) & 1u)) >> 16;
  return (unsigned short)r;
}
__device__ __forceinline__ float bf2f(unsigned short x){
  return __uint_as_float(((unsigned)x) << 16);
}
__device__ __forceinline__ unsigned pack2bf(float lo, float hi){
  unsigned a = (__float_as_uint(lo) + 0x8000u) >> 16;
  unsigned b = (__float_as_uint(hi) + 0x8000u) & 0xFFFF0000u;
  return a | b;
}

// ---------------- CSR build (scan + scatter) ----------------
__global__ void k_scan(const int* __restrict__ cnt, int* __restrict__ off, int* __restrict__ cur){
  __shared__ int part[256];
  int t = threadIdx.x;
  int local[16];
  int s = 0;
  #pragma unroll
  for (int i = 0; i < 16; i++){ local[i] = s; s += cnt[t * 16 + i]; }
  part[t] = s; __syncthreads();
  for (int o = 1; o < 256; o <<= 1){
    int v = (t >= o) ? part[t - o] : 0;
    __syncthreads();
    part[t] += v;
    __syncthreads();
  }
  int base = part[t] - s;
  #pragma unroll
  for (int i = 0; i < 16; i++){ int o = base + local[i]; off[t * 16 + i] = o; cur[t * 16 + i] = o; }
  if (t == 255) off[NN] = part[255];
}

__global__ void k_scatter(const int* __restrict__ ei, const float* __restrict__ ea,
                          int* __restrict__ cur,
                          int* __restrict__ srcs, float* __restrict__ eas4){
  int e = blockIdx.x * 256 + threadIdx.x;
  if (e < EE){
    int d = ei[EE + e];
    int p = atomicAdd(&cur[d], 1);
    srcs[p] = ei[e];
    float4 a = *(const float4*)(ea + e * 4);
    *(float4*)(eas4 + p * 4) = a;
  }
}

// ---------------- one-shot prep + node/global encoder (merged) ----------------
__global__ void k_wprep_enc(const float* __restrict__ Wih, const float* __restrict__ Whh,
                            const float* __restrict__ Wl, const float* __restrict__ Wr,
                            const float* __restrict__ Win, const float* __restrict__ Wout,
                            const float* __restrict__ tiles,
                            const float* __restrict__ bl, const float* __restrict__ br,
                            const float* __restrict__ ea,
                            const float* __restrict__ mvW1, const float* __restrict__ frW1,
                            unsigned short* __restrict__ wbuf, unsigned short* __restrict__ tilesb,
                            float* __restrict__ blrc,
                            unsigned short* __restrict__ wbE, unsigned short* __restrict__ eab,
                            int* __restrict__ cnt, float* __restrict__ gsum,
                            const float* __restrict__ x, const float* __restrict__ tf,
                            const float* __restrict__ neW, const float* __restrict__ neb,
                            const float* __restrict__ neg, const float* __restrict__ nebe,
                            const float* __restrict__ u, const float* __restrict__ geW,
                            const float* __restrict__ geb, const float* __restrict__ geg,
                            const float* __restrict__ gebe,
                            float* __restrict__ h, unsigned short* __restrict__ hb){
  int t = threadIdx.x;
  if (blockIdx.x < WPB){
    int i = blockIdx.x * 256 + t;
    if (i < 49152){ wbuf[i] = f2bf(Wih[i]); }
    else if (i < 98304){ int j = i - 49152; wbuf[49152 + j] = f2bf(Whh[j]); }
    else if (i < 229376){
      int j = i - 98304;
      int l = j >> 15, rem = j & 32767, m = rem >> 7, k = rem & 127;
      float v = (m < 128) ? Wl[l * 16384 + m * 128 + k] : Wr[l * 16384 + (m - 128) * 128 + k];
      wbuf[98304 + j] = f2bf(v);
    }
    else if (i < 278528){ int j = i - 229376; wbuf[229376 + j] = f2bf(Win[j]); }
    else if (i < 294912){ int j = i - 278528; wbuf[278528 + j] = f2bf(Wout[j]); }
    else if (i < 819200){ int j = i - 294912; tilesb[j] = f2bf(tiles[j]); }
    else if (i < 820224){
      int j = i - 819200;
      int l = j >> 8, m = j & 255;
      blrc[j] = (m < 128) ? bl[l * 128 + m] : br[l * 128 + m - 128];
    }
    else if (i < 896000){
      int j = i - 820224;
      int n = j / KPAD, k = j - n * KPAD;
      float v = 0.0f;
      if (k < 2 * HH + EFEAT) v = (n < HH) ? mvW1[n * (2 * HH + EFEAT) + k]
                                           : frW1[(n - HH) * (2 * HH + EFEAT) + k];
      wbE[j] = f2bf(v);
    }
    else if (i < 1158144){
      int j = i - 896000;
      eab[j] = f2bf(ea[j]);
    }
    else if (i < 1162240){ cnt[i - 1158144] = 0; }
    else if (i < 1162497){ gsum[i - 1162240] = 0.0f; }
    return;
  }
  __shared__ float red[256];
  __shared__ float xs[2][NFEAT + 1];
  __shared__ float us[GFEAT];
  int nb = blockIdx.x - WPB;
  int half = t >> 7, j = t & 127;
  int n = nb * 2 + half;
  if (j < NFEAT) xs[half][j] = x[n * NFEAT + j];
  if (j == NFEAT) xs[half][NFEAT] = tf[0];
  if (t < GFEAT) us[t] = u[t];
  __syncthreads();
  int rb = half * 128;
  float ua = geb[j];
  #pragma unroll
  for (int k = 0; k < GFEAT; k++) ua += us[k] * geW[j * GFEAT + k];
  red[rb + j] = ua; __syncthreads();
  #pragma unroll
  for (int s = 64; s > 0; s >>= 1){ if (j < s) red[rb + j] += red[rb + j + s]; __syncthreads(); }
  float umu = red[rb] * (1.0f / HH); __syncthreads();
  float ud = ua - umu;
  red[rb + j] = ud * ud; __syncthreads();
  #pragma unroll
  for (int s = 64; s > 0; s >>= 1){ if (j < s) red[rb + j] += red[rb + j + s]; __syncthreads(); }
  float uvar = red[rb] * (1.0f / HH); __syncthreads();
  float uej = gelu_f(ud * rsqrtf(uvar + 1e-5f) * geg[j] + gebe[j]);
  float acc = neb[j];
  #pragma unroll
  for (int k = 0; k < NFEAT + 1; k++) acc += xs[half][k] * neW[j * (NFEAT + 1) + k];
  red[rb + j] = acc; __syncthreads();
  #pragma unroll
  for (int s = 64; s > 0; s >>= 1){ if (j < s) red[rb + j] += red[rb + j + s]; __syncthreads(); }
  float mu = red[rb] * (1.0f / HH); __syncthreads();
  float d = acc - mu;
  red[rb + j] = d * d; __syncthreads();
  #pragma unroll
  for (int s = 64; s > 0; s >>= 1){ if (j < s) red[rb + j] += red[rb + j + s]; __syncthreads(); }
  float var = red[rb] * (1.0f / HH);
  float r = gelu_f(d * rsqrtf(var + 1e-5f) * neg[j] + nebe[j]) + uej;
  h[n * HH + j] = r;
  hb[n * HH + j] = f2bf(r);
}

// ---------------- shared GEMM core (64 rows x 128 cols, K=128) ----------------
__device__ __forceinline__ void gemm_core(const unsigned short* __restrict__ Xb, int n0,
                                          const unsigned short* __restrict__ Wb, int m0,
                                          unsigned short* Xs, f32x4 acc[8]){
  int t = threadIdx.x;
  #pragma unroll
  for (int k2 = 0; k2 < 4; k2++){
    int v = t + k2 * 256;
    int r = v >> 4, c8 = v & 15;
    *(uint4*)(Xs + r * XSTR + c8 * 8) = *(const uint4*)(Xb + (n0 + r) * 128 + c8 * 8);
  }
  __syncthreads();
  int ln = t & 63, w = t >> 6, lm = ln & 15, quad = ln >> 4;
  const unsigned short* abase = Xs + (16 * w + lm) * XSTR + quad * 8;
  const unsigned short* bbase = Wb + (m0 + lm) * 128 + quad * 8;
  UB af[4];
  #pragma unroll
  for (int ks = 0; ks < 4; ks++) af[ks].u = *(const uint4*)(abase + ks * 32);
  #pragma unroll
  for (int i = 0; i < 8; i++) acc[i] = (f32x4){0.f, 0.f, 0.f, 0.f};
  #pragma unroll
  for (int t2 = 0; t2 < 8; t2++){
    #pragma unroll
    for (int ks = 0; ks < 4; ks++){
      UB bu;
      bu.u = *(const uint4*)(bbase + t2 * 16 * 128 + ks * 32);
      acc[t2] = __builtin_amdgcn_mfma_f32_16x16x32_bf16(af[ks].v, bu.v, acc[t2], 0, 0, 0);
    }
  }
}

// GRU: both projections in one launch
__global__ __launch_bounds__(256) void k_gru_lin(const unsigned short* __restrict__ hb,
                                                 const unsigned short* __restrict__ tilesb,
                                                 const unsigned short* __restrict__ Wihb,
                                                 const unsigned short* __restrict__ Whhb,
                                                 const float* __restrict__ bih,
                                                 const float* __restrict__ bhh,
                                                 float* __restrict__ gi, float* __restrict__ gh){
  __shared__ __align__(16) unsigned short Xs[64 * XSTR];
  int z = blockIdx.z;
  const unsigned short* Xb = z ? tilesb : hb;
  const unsigned short* Wb = z ? Whhb : Wihb;
  const float* bias = z ? bhh : bih;
  float* Y = z ? gh : gi;
  int t = threadIdx.x;
  int n0 = blockIdx.x * 64, m0 = blockIdx.y * 128;
  f32x4 acc[8];
  gemm_core(Xb, n0, Wb, m0, Xs, acc);
  int ln = t & 63, w = t >> 6, lm = ln & 15, quad = ln >> 4;
  #pragma unroll
  for (int t2 = 0; t2 < 8; t2++){
    float bv = bias[m0 + t2 * 16 + lm];
    #pragma unroll
    for (int r = 0; r < 4; r++){
      Y[(n0 + 16 * w + quad * 4 + r) * 384 + m0 + t2 * 16 + lm] = acc[t2][r] + bv;
    }
  }
}

// GAT projection: bf16 out
__global__ __launch_bounds__(256) void k_lin_gat(const unsigned short* __restrict__ Xb,
                                                 const unsigned short* __restrict__ Wb,
                                                 const float* __restrict__ bias,
                                                 unsigned short* __restrict__ Y){
  __shared__ __align__(16) unsigned short Xs[64 * XSTR];
  int t = threadIdx.x;
  int n0 = blockIdx.x * 64, m0 = blockIdx.y * 128;
  f32x4 acc[8];
  gemm_core(Xb, n0, Wb, m0, Xs, acc);
  int ln = t & 63, w = t >> 6, lm = ln & 15, quad = ln >> 4;
  #pragma unroll
  for (int t2 = 0; t2 < 8; t2++){
    float bv = bias[m0 + t2 * 16 + lm];
    #pragma unroll
    for (int r = 0; r < 4; r++){
      Y[(n0 + 16 * w + quad * 4 + r) * 256 + m0 + t2 * 16 + lm] = f2bf(acc[t2][r] + bv);
    }
  }
}

// QKV projection with fused post
__global__ __launch_bounds__(256) void k_lin_qkv(const unsigned short* __restrict__ Xb,
                                                 const unsigned short* __restrict__ Wb,
                                                 const float* __restrict__ bias,
                                                 unsigned short* __restrict__ qb,
                                                 unsigned short* __restrict__ kb,
                                                 unsigned short* __restrict__ vt){
  __shared__ __align__(16) unsigned short Xs[64 * XSTR];
  int t = threadIdx.x;
  int n0 = blockIdx.x * 64, m0 = blockIdx.y * 128;
  f32x4 acc[8];
  gemm_core(Xb, n0, Wb, m0, Xs, acc);
  int ln = t & 63, w = t >> 6, lm = ln & 15, quad = ln >> 4;
  int nb = n0 + 16 * w + quad * 4;
  const float scale = 0.17677669529663687f;
  if (blockIdx.y == 0){
    #pragma unroll
    for (int t2 = 0; t2 < 8; t2++){
      int m = t2 * 16 + lm;
      float bv = bias[m];
      #pragma unroll
      for (int r = 0; r < 4; r++) qb[(nb + r) * HH + m] = f2bf(acc[t2][r] + bv);
    }
  } else if (blockIdx.y == 1){
    #pragma unroll
    for (int t2 = 0; t2 < 8; t2++){
      int m = t2 * 16 + lm;
      float bv = bias[128 + m];
      #pragma unroll
      for (int r = 0; r < 4; r++) kb[(nb + r) * HH + m] = f2bf((acc[t2][r] + bv) * scale);
    }
  } else {
    #pragma unroll
    for (int t2 = 0; t2 < 8; t2++){
      int m = t2 * 16 + lm;
      float bv = bias[256 + m];
      uint2 p;
      p.x = pack2bf(acc[t2][0] + bv, acc[t2][1] + bv);
      p.y = pack2bf(acc[t2][2] + bv, acc[t2][3] + bv);
      *(uint2*)(vt + m * NN + nb) = p;
    }
  }
}

// ---------------- GRU combine + edge histogram (merged) ----------------
__global__ void k_gru_comb(const float* __restrict__ gi, const float* __restrict__ gh,
                           const float* __restrict__ tiles, float* __restrict__ h,
                           unsigned short* __restrict__ hb, float* __restrict__ out_tiles,
                           const int* __restrict__ ei, int* __restrict__ cnt){
  int bid = blockIdx.x, t = threadIdx.x;
  if (bid >= NN * HH / 256){
    int e = (bid - NN * HH / 256) * 256 + t;
    if (e < EE) atomicAdd(&cnt[ei[EE + e]], 1);
    return;
  }
  int idx = bid * 256 + t;
  int n = idx >> 7, j = idx & 127;
  float ir = gi[n * 384 + j], iz = gi[n * 384 + 128 + j], inn = gi[n * 384 + 256 + j];
  float hr = gh[n * 384 + j], hz = gh[n * 384 + 128 + j], hn = gh[n * 384 + 256 + j];
  float r = sigm_fast(ir + hr), z = sigm_fast(iz + hz);
  float nn2 = tanh_fast(inn + r * hn);
  float ts = tiles[idx];
  float hnew = (1.0f - z) * nn2 + z * ts;
  h[idx] = hnew;
  hb[idx] = f2bf(hnew);
  out_tiles[idx] = hnew;
}

// ---------------- fused GAT score + aggregate + residual + LN ----------------
__global__ __launch_bounds__(256) void k_gat_agg(
    const unsigned short* __restrict__ xlrb,
    const int* __restrict__ off, const int* __restrict__ srcs,
    const float* __restrict__ eas4,
    const float* __restrict__ We, const float* __restrict__ att,
    const float* __restrict__ bias, const float* __restrict__ g,
    const float* __restrict__ b, float* __restrict__ h,
    unsigned short* __restrict__ hb){
  int t = threadIdx.x, w = t >> 6, j = t & 63;
  int n = blockIdx.x * 4 + w;
  int p0 = __builtin_amdgcn_readfirstlane(off[n]);
  int p1 = __builtin_amdgcn_readfirstlane(off[n + 1]);
  int c0 = 2 * j;
  float4 w0 = ((const float4*)We)[c0];
  float4 w1 = ((const float4*)We)[c0 + 1];
  float at0 = att[c0], at1 = att[c0 + 1];
  unsigned xr = *(const unsigned*)(xlrb + n * 256 + 128 + c0);
  float xr0 = bf2f((unsigned short)xr), xr1 = bf2f((unsigned short)(xr >> 16));
  float den = 0.f, a0 = 0.f, a1 = 0.f;
  int p = p0;
  for (; p + 4 <= p1; p += 4){
    int s0 = srcs[p], s1 = srcs[p + 1], s2 = srcs[p + 2], s3 = srcs[p + 3];
    unsigned x0 = *(const unsigned*)(xlrb + s0 * 256 + c0);
    unsigned x1 = *(const unsigned*)(xlrb + s1 * 256 + c0);
    unsigned x2 = *(const unsigned*)(xlrb + s2 * 256 + c0);
    unsigned x3 = *(const unsigned*)(xlrb + s3 * 256 + c0);
    float4 ev0 = *(const float4*)(eas4 + p * 4);
    float4 ev1 = *(const float4*)(eas4 + (p + 1) * 4);
    float4 ev2 = *(const float4*)(eas4 + (p + 2) * 4);
    float4 ev3 = *(const float4*)(eas4 + (p + 3) * 4);
    float x00 = bf2f((unsigned short)x0), x01 = bf2f((unsigned short)(x0 >> 16));
    float x10 = bf2f((unsigned short)x1), x11 = bf2f((unsigned short)(x1 >> 16));
    float x20 = bf2f((unsigned short)x2), x21 = bf2f((unsigned short)(x2 >> 16));
    float x30 = bf2f((unsigned short)x3), x31 = bf2f((unsigned short)(x3 >> 16));
    float vA0 = x00 + xr0 + ev0.x * w0.x + ev0.y * w0.y + ev0.z * w0.z + ev0.w * w0.w;
    float vA1 = x01 + xr1 + ev0.x * w1.x + ev0.y * w1.y + ev0.z * w1.z + ev0.w * w1.w;
    float vB0 = x10 + xr0 + ev1.x * w0.x + ev1.y * w0.y + ev1.z * w0.z + ev1.w * w0.w;
    float vB1 = x11 + xr1 + ev1.x * w1.x + ev1.y * w1.y + ev1.z * w1.z + ev1.w * w1.w;
    float vC0 = x20 + xr0 + ev2.x * w0.x + ev2.y * w0.y + ev2.z * w0.z + ev2.w * w0.w;
    float vC1 = x21 + xr1 + ev2.x * w1.x + ev2.y * w1.y + ev2.z * w1.z + ev2.w * w1.w;
    float vD0 = x30 + xr0 + ev3.x * w0.x + ev3.y * w0.y + ev3.z * w0.z + ev3.w * w0.w;
    float vD1 = x31 + xr1 + ev3.x * w1.x + ev3.y * w1.y + ev3.z * w1.z + ev3.w * w1.w;
    vA0 = vA0 > 0.f ? vA0 : 0.2f * vA0;  vA1 = vA1 > 0.f ? vA1 : 0.2f * vA1;
    vB0 = vB0 > 0.f ? vB0 : 0.2f * vB0;  vB1 = vB1 > 0.f ? vB1 : 0.2f * vB1;
    vC0 = vC0 > 0.f ? vC0 : 0.2f * vC0;  vC1 = vC1 > 0.f ? vC1 : 0.2f * vC1;
    vD0 = vD0 > 0.f ? vD0 : 0.2f * vD0;  vD1 = vD1 > 0.f ? vD1 : 0.2f * vD1;
    float sA = vA0 * at0 + vA1 * at1;
    float sB = vB0 * at0 + vB1 * at1;
    float sC = vC0 * at0 + vC1 * at1;
    float sD = vD0 * at0 + vD1 * at1;
    #pragma unroll
    for (int d = 1; d < 16; d <<= 1){
      sA += __shfl_xor(sA, d); sB += __shfl_xor(sB, d);
      sC += __shfl_xor(sC, d); sD += __shfl_xor(sD, d);
    }
    float eA = __expf(sA), eB = __expf(sB), eC = __expf(sC), eD = __expf(sD);
    den += (eA + eB) + (eC + eD);
    a0 += eA * x00 + eB * x10 + eC * x20 + eD * x30;
    a1 += eA * x01 + eB * x11 + eC * x21 + eD * x31;
  }
  for (; p < p1; p++){
    int s0 = srcs[p];
    float4 ev0 = *(const float4*)(eas4 + p * 4);
    unsigned x0 = *(const unsigned*)(xlrb + s0 * 256 + c0);
    float x00 = bf2f((unsigned short)x0), x01 = bf2f((unsigned short)(x0 >> 16));
    float vA0 = x00 + xr0 + ev0.x * w0.x + ev0.y * w0.y + ev0.z * w0.z + ev0.w * w0.w;
    float vA1 = x01 + xr1 + ev0.x * w1.x + ev0.y * w1.y + ev0.z * w1.z + ev0.w * w1.w;
    vA0 = vA0 > 0.f ? vA0 : 0.2f * vA0;  vA1 = vA1 > 0.f ? vA1 : 0.2f * vA1;
    float sA = vA0 * at0 + vA1 * at1;
    #pragma unroll
    for (int d = 1; d < 16; d <<= 1) sA += __shfl_xor(sA, d);
    float eA = __expf(sA);
    den += eA;
    a0 += eA * x00;
    a1 += eA * x01;
  }
  float dinv = 1.0f / (den + 1e-16f);
  float2 hv = *(const float2*)(h + n * HH + c0);
  float v0 = hv.x + a0 * dinv + bias[c0];
  float v1 = hv.y + a1 * dinv + bias[c0 + 1];
  float s = v0 + v1;
  #pragma unroll
  for (int d = 1; d < 64; d <<= 1) s += __shfl_xor(s, d);
  float mu = s * (1.0f / HH);
  float d0 = v0 - mu, d1 = v1 - mu;
  float q = d0 * d0 + d1 * d1;
  #pragma unroll
  for (int d = 1; d < 64; d <<= 1) q += __shfl_xor(q, d);
  float rstd = rsqrtf(q * (1.0f / HH) + 1e-5f);
  float o0 = d0 * rstd * g[c0] + b[c0];
  float o1 = d1 * rstd * g[c0 + 1] + b[c0 + 1];
  float2 ov; ov.x = o0; ov.y = o1;
  *(float2*)(h + n * HH + c0) = ov;
  unsigned pk = ((unsigned)f2bf(o0)) | (((unsigned)f2bf(o1)) << 16);
  *(unsigned*)(hb + n * HH + c0) = pk;
}

// ---------------- flash attention: 128-key double-buffered LDS chunks ----------------
__global__ __launch_bounds__(256, 4) void k_attn_flash(
    const unsigned short* __restrict__ qb, const unsigned short* __restrict__ kb,
    const unsigned short* __restrict__ vt,
    float* __restrict__ pden, float* __restrict__ pacc){
  __shared__ __align__(16) unsigned short Kls[2][128 * KSTR];
  __shared__ __align__(16) unsigned short Vls[2][32 * VSTR];
  int t = threadIdx.x, w = t >> 6, ln = t & 63;
  int c = ln & 15, qd = ln >> 4;
  int hh = blockIdx.y, ks = blockIdx.z;
  int q0 = blockIdx.x * 64 + w * 16;
  UB qf; qf.u = *(const uint4*)(qb + (q0 + c) * HH + hh * HDIM + qd * 8);
  f32x4 o0a = {0,0,0,0}, o1a = {0,0,0,0}, o0b = {0,0,0,0}, o1b = {0,0,0,0};
  float denp = 0.f;
  int srcA = c + ((qd & 1) << 5);
  int srcB = srcA + 16;
  bool hi = qd >= 2;
  int kk2 = t >> 1, kp2 = (t & 1) * 2;
  int vr2 = t >> 3, vc2 = (t & 7) * 2;
  const unsigned short* kg = kb + hh * HDIM + kp2 * 8;
  const unsigned short* vg = vt + (hh * HDIM + vr2) * NN + vc2 * 8;

  auto stage = [&](int buf, int k0){
    uint4 ka = *(const uint4*)(kg + (k0 + kk2) * HH);
    uint4 kb4 = *(const uint4*)(kg + (k0 + kk2) * HH + 8);
    uint4 va = *(const uint4*)(vg + k0);
    uint4 vb4 = *(const uint4*)(vg + k0 + 8);
    *(uint4*)(&Kls[buf][kk2 * KSTR + kp2 * 8]) = ka;
    *(uint4*)(&Kls[buf][kk2 * KSTR + kp2 * 8 + 8]) = kb4;
    *(uint4*)(&Vls[buf][vr2 * VSTR + vc2 * 8]) = va;
    *(uint4*)(&Vls[buf][vr2 * VSTR + vc2 * 8 + 8]) = vb4;
  };
  auto comp = [&](int buf, int hs, f32x4& O0, f32x4& O1){
    UB kf0, kf1, vf0, vf1, pt;
    kf0.u = *(const uint4*)(&Kls[buf][(hs * 32 + c) * KSTR + qd * 8]);
    kf1.u = *(const uint4*)(&Kls[buf][(hs * 32 + 16 + c) * KSTR + qd * 8]);
    vf0.u = *(const uint4*)(&Vls[buf][c * VSTR + hs * 32 + qd * 8]);
    vf1.u = *(const uint4*)(&Vls[buf][(16 + c) * VSTR + hs * 32 + qd * 8]);
    f32x4 s0 = {0,0,0,0}, s1 = {0,0,0,0};
    s0 = __builtin_amdgcn_mfma_f32_16x16x32_bf16(kf0.v, qf.v, s0, 0, 0, 0);
    s1 = __builtin_amdgcn_mfma_f32_16x16x32_bf16(kf1.v, qf.v, s1, 0, 0, 0);
    float e00 = __expf(s0[0]), e01 = __expf(s0[1]), e02 = __expf(s0[2]), e03 = __expf(s0[3]);
    float e10 = __expf(s1[0]), e11 = __expf(s1[1]), e12 = __expf(s1[2]), e13 = __expf(s1[3]);
    denp += (e00 + e01) + (e02 + e03) + (e10 + e11) + (e12 + e13);
    int p00 = (int)pack2bf(e00, e01), p01 = (int)pack2bf(e02, e03);
    int p10 = (int)pack2bf(e10, e11), p11 = (int)pack2bf(e12, e13);
    int a00 = __shfl(p00, srcA), a01 = __shfl(p01, srcA);
    int b00 = __shfl(p00, srcB), b01 = __shfl(p01, srcB);
    int a10 = __shfl(p10, srcA), a11 = __shfl(p11, srcA);
    int b10 = __shfl(p10, srcB), b11 = __shfl(p11, srcB);
    pt.u.x = (unsigned)(hi ? a10 : a00);
    pt.u.y = (unsigned)(hi ? a11 : a01);
    pt.u.z = (unsigned)(hi ? b10 : b00);
    pt.u.w = (unsigned)(hi ? b11 : b01);
    O0 = __builtin_amdgcn_mfma_f32_16x16x32_bf16(vf0.v, pt.v, O0, 0, 0, 0);
    O1 = __builtin_amdgcn_mfma_f32_16x16x32_bf16(vf1.v, pt.v, O1, 0, 0, 0);
  };

  const int kbeg = ks * (NN / KS);
  const int NIT = (NN / KS) / 128;   // 8
  stage(0, kbeg);
  __syncthreads();
  for (int it = 0; it < NIT; it++){
    int buf = it & 1;
    if (it + 1 < NIT){
      int kn = kbeg + (it + 1) * 128;
      uint4 ka = *(const uint4*)(kg + (kn + kk2) * HH);
      uint4 kb4 = *(const uint4*)(kg + (kn + kk2) * HH + 8);
      uint4 va = *(const uint4*)(vg + kn);
      uint4 vb4 = *(const uint4*)(vg + kn + 8);
      comp(buf, 0, o0a, o1a);
      comp(buf, 1, o0b, o1b);
      comp(buf, 2, o0a, o1a);
      comp(buf, 3, o0b, o1b);
      *(uint4*)(&Kls[buf ^ 1][kk2 * KSTR + kp2 * 8]) = ka;
      *(uint4*)(&Kls[buf ^ 1][kk2 * KSTR + kp2 * 8 + 8]) = kb4;
      *(uint4*)(&Vls[buf ^ 1][vr2 * VSTR + vc2 * 8]) = va;
      *(uint4*)(&Vls[buf ^ 1][vr2 * VSTR + vc2 * 8 + 8]) = vb4;
    } else {
      comp(buf, 0, o0a, o1a);
      comp(buf, 1, o0b, o1b);
      comp(buf, 2, o0a, o1a);
      comp(buf, 3, o0b, o1b);
    }
    __syncthreads();
  }

  f32x4 o0 = o0a + o0b, o1 = o1a + o1b;
  denp += __shfl_xor(denp, 16);
  denp += __shfl_xor(denp, 32);
  int pi = ((q0 + c) * NHEADS + hh) * KS + ks;
  if (qd == 0) pden[pi] = denp;
  #pragma unroll
  for (int r = 0; r < 4; r++){
    pacc[pi * HDIM + qd * 4 + r]      = o0[r];
    pacc[pi * HDIM + 16 + qd * 4 + r] = o1[r];
  }
}

// fused: combine partials -> MFMA proj -> residual+LN -> h,hb + value-head pooling
__global__ __launch_bounds__(256) void k_attn_out(
    const float* __restrict__ pden, const float* __restrict__ pacc,
    const unsigned short* __restrict__ Wb, const float* __restrict__ bout,
    const float* __restrict__ g, const float* __restrict__ b,
    const unsigned char* __restrict__ mask,
    float* __restrict__ h, unsigned short* __restrict__ hb,
    float* __restrict__ gsum, float* __restrict__ msum, float* __restrict__ mcnt){
  __shared__ __align__(16) unsigned short Xs[64 * XSTR];
  __shared__ float colg[128], colm[128], colc;
  int t = threadIdx.x;
  int n0 = blockIdx.x * 64;
  if (t < 128){ colg[t] = 0.f; colm[t] = 0.f; }
  if (t == 128) colc = 0.f;
  for (int idx = t; idx < 64 * 128; idx += 256){
    int r = idx >> 7, j = idx & 127;
    int n = n0 + r, hh = j >> 5, d = j & 31;
    float ds = 0.f, as = 0.f;
    #pragma unroll
    for (int ks2 = 0; ks2 < KS; ks2++){
      int pi = (n * NHEADS + hh) * KS + ks2;
      ds += pden[pi];
      as += pacc[pi * HDIM + d];
    }
    Xs[r * XSTR + j] = f2bf(as / ds);
  }
  __syncthreads();
  int ln = t & 63, w = t >> 6, lm = ln & 15, quad = ln >> 4;
  const unsigned short* abase = Xs + (16 * w + lm) * XSTR + quad * 8;
  const unsigned short* bbase = Wb + lm * 128 + quad * 8;
  UB af[4];
  #pragma unroll
  for (int ks2 = 0; ks2 < 4; ks2++) af[ks2].u = *(const uint4*)(abase + ks2 * 32);
  f32x4 acc[8];
  #pragma unroll
  for (int i = 0; i < 8; i++) acc[i] = (f32x4){0.f, 0.f, 0.f, 0.f};
  #pragma unroll
  for (int t2 = 0; t2 < 8; t2++){
    #pragma unroll
    for (int ks2 = 0; ks2 < 4; ks2++){
      UB bu;
      bu.u = *(const uint4*)(bbase + t2 * 16 * 128 + ks2 * 32);
      acc[t2] = __builtin_amdgcn_mfma_f32_16x16x32_bf16(af[ks2].v, bu.v, acc[t2], 0, 0, 0);
    }
  }
  int nb = n0 + 16 * w + quad * 4;
  float val[8][4];
  #pragma unroll
  for (int t2 = 0; t2 < 8; t2++){
    int m = t2 * 16 + lm;
    float bv = bout[m];
    #pragma unroll
    for (int r = 0; r < 4; r++)
      val[t2][r] = acc[t2][r] + bv + h[(nb + r) * HH + m];
  }
  float mu[4], rs[4];
  #pragma unroll
  for (int r = 0; r < 4; r++){
    float s = 0.f;
    #pragma unroll
    for (int t2 = 0; t2 < 8; t2++) s += val[t2][r];
    s += __shfl_xor(s, 1); s += __shfl_xor(s, 2);
    s += __shfl_xor(s, 4); s += __shfl_xor(s, 8);
    mu[r] = s * (1.0f / HH);
  }
  #pragma unroll
  for (int r = 0; r < 4; r++){
    float s = 0.f;
    #pragma unroll
    for (int t2 = 0; t2 < 8; t2++){ float d2 = val[t2][r] - mu[r]; s += d2 * d2; }
    s += __shfl_xor(s, 1); s += __shfl_xor(s, 2);
    s += __shfl_xor(s, 4); s += __shfl_xor(s, 8);
    rs[r] = rsqrtf(s * (1.0f / HH) + 1e-5f);
  }
  uchar4 mk = *(const uchar4*)(mask + nb);
  float mkf[4] = { mk.x ? 1.f : 0.f, mk.y ? 1.f : 0.f, mk.z ? 1.f : 0.f, mk.w ? 1.f : 0.f };
  #pragma unroll
  for (int t2 = 0; t2 < 8; t2++){
    int m = t2 * 16 + lm;
    float gm = g[m], bm = b[m];
    float sg = 0.f, sm = 0.f;
    #pragma unroll
    for (int r = 0; r < 4; r++){
      float o = (val[t2][r] - mu[r]) * rs[r] * gm + bm;
      h[(nb + r) * HH + m] = o;
      hb[(nb + r) * HH + m] = f2bf(o);
      sg += o;
      sm += mkf[r] * o;
    }
    sg += __shfl_xor(sg, 16); sg += __shfl_xor(sg, 32);
    sm += __shfl_xor(sm, 16); sm += __shfl_xor(sm, 32);
    if (quad == 0){
      atomicAdd(&colg[m], sg);
      atomicAdd(&colm[m], sm);
    }
  }
  if (lm == 0){
    float c = mkf[0] + mkf[1] + mkf[2] + mkf[3];
    atomicAdd(&colc, c);
  }
  __syncthreads();
  if (t < 128){
    atomicAdd(&gsum[t], colg[t]);
    atomicAdd(&msum[t], colm[t]);
  }
  if (t == 128) atomicAdd(mcnt, colc);
}

// ---------------- edge heads via MFMA + value head (merged) ----------------
// staging now via global_load_lds: per wave, 32 direct-to-LDS 256B row copies
// (wave-uniform LDS base, lane x 4B), no VGPR round trip.
__global__ __launch_bounds__(256, 4) void k_edge_mfma(
    const unsigned short* __restrict__ hb, const unsigned short* __restrict__ eab,
    const int* __restrict__ ei, const unsigned short* __restrict__ wb,
    const float* __restrict__ mvb1, const float* __restrict__ frb1,
    const float* __restrict__ mvW2, const float* __restrict__ mvb2,
    const float* __restrict__ frW2, const float* __restrict__ frb2,
    const float* __restrict__ gsum, const float* __restrict__ msum,
    const float* __restrict__ mcnt,
    const float* __restrict__ vlW1, const float* __restrict__ vlb1,
    const float* __restrict__ vlW2, const float* __restrict__ vlb2,
    float* __restrict__ out, float* __restrict__ out_val){
  __shared__ __align__(16) unsigned short As[64 * KPAD];
  __shared__ float am[64], a0[64], a1[64];
  __shared__ float red[128];
  __shared__ float vin[256];
  int t = threadIdx.x;
  if (blockIdx.x == EE / 64){
    int j = t & 127;
    if (t < 128){
      float gp = gsum[j] * (1.0f / NN);
      float as2 = msum[j] * (1.0f / NN);
      float ac = fmaxf(mcnt[0] * (1.0f / NN), 1e-6f);
      vin[j] = gp; vin[HH + j] = as2 / ac;
    }
    __syncthreads();
    float hv = 0.f;
    if (t < 128){
      float acc2 = vlb1[j];
      const float* wv = &vlW1[j * 256];
      #pragma unroll 4
      for (int k = 0; k < 256; k++) acc2 += vin[k] * wv[k];
      hv = gelu_f(acc2) * vlW2[j];
    }
    if (t < 128) red[j] = hv;
    __syncthreads();
    #pragma unroll
    for (int s = 64; s > 0; s >>= 1){
      if (t < s) red[t] += red[t + s];
      __syncthreads();
    }
    if (t == 0) out_val[0] = red[0] + vlb2[0];
    return;
  }
  int e0 = blockIdx.x * 64;
  int ln = t & 63, w = t >> 6, lm = ln & 15, quad = ln >> 4;
  if (t < 64){ am[t] = 0.f; a0[t] = 0.f; a1[t] = 0.f; }
  // ---- staging: wave w stages edges [16w, 16w+16), 2 rows each via global_load_lds ----
  {
    int el0 = w * 16;
    #pragma unroll 4
    for (int i = 0; i < 16; i++){
      int el = el0 + i;
      int e = e0 + el;
      int ns = ei[e];
      int nd = ei[EE + e];
      __builtin_amdgcn_global_load_lds(
        (const __attribute__((address_space(1))) unsigned*)(hb + ns * HH) + ln,
        (__attribute__((address_space(3))) unsigned*)(As + el * KPAD), 4, 0, 0);
      __builtin_amdgcn_global_load_lds(
        (const __attribute__((address_space(1))) unsigned*)(hb + nd * HH) + ln,
        (__attribute__((address_space(3))) unsigned*)(As + el * KPAD + 128), 4, 0, 0);
    }
  }
  // tail: edge attrs + zero pad (plain LDS writes, drained by the barrier)
  if ((t & 3) == 0){
    int el = t >> 2;
    int e = e0 + el;
    unsigned short* tail = As + el * KPAD + 256;
    tail[0] = eab[e * 4];     tail[1] = eab[e * 4 + 1];
    tail[2] = eab[e * 4 + 2]; tail[3] = eab[e * 4 + 3];
    #pragma unroll
    for (int i = 4; i < KPAD - 256; i++) tail[i] = 0;
  }
  const unsigned short* bbase = wb + (w * 64 + lm) * KPAD + quad * 8;
  f32x4 acc[4][4];
  #pragma unroll
  for (int rt = 0; rt < 4; rt++)
    #pragma unroll
    for (int t2 = 0; t2 < 4; t2++) acc[rt][t2] = (f32x4){0.f, 0.f, 0.f, 0.f};
  __syncthreads();
  #pragma unroll
  for (int ks = 0; ks < 9; ks++){
    UB bf[4], af[4];
    #pragma unroll
    for (int t2 = 0; t2 < 4; t2++) bf[t2].u = *(const uint4*)(bbase + t2 * 16 * KPAD + ks * 32);
    #pragma unroll
    for (int rt = 0; rt < 4; rt++) af[rt].u = *(const uint4*)(As + (16 * rt + lm) * KPAD + quad * 8 + ks * 32);
    #pragma unroll
    for (int rt = 0; rt < 4; rt++)
      #pragma unroll
      for (int t2 = 0; t2 < 4; t2++)
        acc[rt][t2] = __builtin_amdgcn_mfma_f32_16x16x32_bf16(af[rt].v, bf[t2].v, acc[rt][t2], 0, 0, 0);
  }
  if (w < 2){
    #pragma unroll
    for (int rt = 0; rt < 4; rt++){
      #pragma unroll
      for (int r = 0; r < 4; r++){
        float s = 0.f;
        #pragma unroll
        for (int t2 = 0; t2 < 4; t2++){
          int n = w * 64 + t2 * 16 + lm;
          s += gelu_fast(acc[rt][t2][r] + mvb1[n]) * mvW2[n];
        }
        #pragma unroll
        for (int d = 1; d < 16; d <<= 1) s += __shfl_xor(s, d);
        if (lm == 0) atomicAdd(&am[16 * rt + 4 * quad + r], s);
      }
    }
  } else {
    #pragma unroll
    for (int rt = 0; rt < 4; rt++){
      #pragma unroll
      for (int r = 0; r < 4; r++){
        float s0 = 0.f, s1 = 0.f;
        #pragma unroll
        for (int t2 = 0; t2 < 4; t2++){
          int n = (w - 2) * 64 + t2 * 16 + lm;
          float g = gelu_fast(acc[rt][t2][r] + frb1[n]);
          s0 += g * frW2[n];
          s1 += g * frW2[128 + n];
        }
        #pragma unroll
        for (int d = 1; d < 16; d <<= 1){ s0 += __shfl_xor(s0, d); s1 += __shfl_xor(s1, d); }
        if (lm == 0){
          atomicAdd(&a0[16 * rt + 4 * quad + r], s0);
          atomicAdd(&a1[16 * rt + 4 * quad + r], s1);
        }
      }
    }
  }
  __syncthreads();
  if (t < 64){
    int e = e0 + t;
    out[e]          = am[t] + mvb2[0];
    out[EE + e]     = softplus_f(a0[t] + frb2[0]) + 1e-4f;
    out[2 * EE + e] = softplus_f(a1[t] + frb2[1]) + 1e-4f;
  }
}

extern "C" void kernel_launch(void* const* d_in, const int* in_sizes, int n_in,
                              void* d_out, int out_size, void* d_ws, size_t ws_size,
                              hipStream_t stream){
  (void)in_sizes; (void)n_in; (void)out_size; (void)ws_size;
  const float* x        = (const float*)d_in[0];
  const int*   ei       = (const int*)d_in[1];
  const float* ea       = (const float*)d_in[2];
  const float* u        = (const float*)d_in[3];
  const unsigned char* mask = (const unsigned char*)d_in[4];
  const float* tiles    = (const float*)d_in[5];
  const float* tf       = (const float*)d_in[7];
  const float* ne_W  = (const float*)d_in[8];
  const float* ne_b  = (const float*)d_in[9];
  const float* ne_g  = (const float*)d_in[10];
  const float* ne_be = (const float*)d_in[11];
  const float* ge_W  = (const float*)d_in[12];
  const float* ge_b  = (const float*)d_in[13];
  const float* ge_g  = (const float*)d_in[14];
  const float* ge_be = (const float*)d_in[15];
  const float* gru_Wih = (const float*)d_in[16];
  const float* gru_bih = (const float*)d_in[17];
  const float* gru_Whh = (const float*)d_in[18];
  const float* gru_bhh = (const float*)d_in[19];
  const float* gat_Wl  = (const float*)d_in[20];
  const float* gat_bl  = (const float*)d_in[21];
  const float* gat_Wr  = (const float*)d_in[22];
  const float* gat_br  = (const float*)d_in[23];
  const float* gat_We  = (const float*)d_in[24];
  const float* gat_att = (const float*)d_in[25];
  const float* gat_bias= (const float*)d_in[26];
  const float* ln_g    = (const float*)d_in[27];
  const float* ln_b    = (const float*)d_in[28];
  const float* attn_Win = (const float*)d_in[29];
  const float* attn_bin = (const float*)d_in[30];
  const float* attn_Wout= (const float*)d_in[31];
  const float* attn_bout= (const float*)d_in[32];
  const float* lng_g    = (const float*)d_in[33];
  const float* lng_b    = (const float*)d_in[34];
  const float* mv_W1 = (const float*)d_in[35];
  const float* mv_b1 = (const float*)d_in[36];
  const float* mv_W2 = (const float*)d_in[37];
  const float* mv_b2 = (const float*)d_in[38];
  const float* fr_W1 = (const float*)d_in[39];
  const float* fr_b1 = (const float*)d_in[40];
  const float* fr_W2 = (const float*)d_in[41];
  const float* fr_b2 = (const float*)d_in[42];
  const float* vl_W1 = (const float*)d_in[43];
  const float* vl_b1 = (const float*)d_in[44];
  const float* vl_W2 = (const float*)d_in[45];
  const float* vl_b2 = (const float*)d_in[46];

  // ---- workspace layout (f32 elem offsets) ----
  float* ws = (float*)d_ws;
  float* h      = ws;                         // 524288
  float* xlr    = ws + 524288;                // reused: GAT xlrb, attn qb/kb/vt
  unsigned short* hb     = (unsigned short*)(ws + 1572864);
  unsigned short* tilesb = (unsigned short*)(ws + 1835008);
  unsigned short* wbuf   = (unsigned short*)(ws + 2097152);
  unsigned short* Wihb  = wbuf;
  unsigned short* Whhb  = wbuf + 49152;
  unsigned short* Wlrb  = wbuf + 98304;
  unsigned short* Winb  = wbuf + 229376;
  unsigned short* Woutb = wbuf + 278528;
  float* blrc   = ws + 2244608;
  float* gsum   = ws + 2245760;
  float* msum   = ws + 2245888;
  float* mcnt   = ws + 2246016;
  int*   cnt    = (int*)(ws + 2246032);
  int*   off    = cnt + NN;
  int*   cur    = off + NN + 1;
  unsigned short* eab = (unsigned short*)(ws + 2323904);
  unsigned short* wbE = (unsigned short*)(ws + 2454976);
  float* S      = ws + 2492864;               // 3145728 scratch (multi-phase)
  float* gi = S;
  float* gh = S + 1572864;
  float* eas4 = S;                                        // EE*4 f32 CSR-slot attrs
  int*   srcs = (int*)(S + 262144);                       // EE
  unsigned short* xlrb = (unsigned short*)xlr;            // NN*256 bf16
  unsigned short* qb = (unsigned short*)xlr;
  unsigned short* kb = (unsigned short*)(xlr + 262144);
  unsigned short* vt = (unsigned short*)(xlr + 524288 + 16384);
  float* pacc = S + 327680;                               // NN*4*KS*32 f32
  float* pden = S + 327680 + 2097152;                     // NN*4*KS

  float* out       = (float*)d_out;
  float* out_val   = out + 3 * EE;
  float* out_tiles = out + 3 * EE + 1;

  // one-shot bf16 prep + zero-init + node/global encoder (merged)
  k_wprep_enc<<<WPB + NN / 2, 256, 0, stream>>>(gru_Wih, gru_Whh, gat_Wl, gat_Wr,
                                                attn_Win, attn_Wout, tiles,
                                                gat_bl, gat_br, ea, mv_W1, fr_W1,
                                                wbuf, tilesb, blrc, wbE, eab,
                                                cnt, gsum,
                                                x, tf, ne_W, ne_b, ne_g, ne_be,
                                                u, ge_W, ge_b, ge_g, ge_be, h, hb);

  // GRU via MFMA (both projections in one launch)
  { dim3 g(NN / 64, 3, 2);
    k_gru_lin<<<g, 256, 0, stream>>>(hb, tilesb, Wihb, Whhb, gru_bih, gru_bhh, gi, gh); }
  // GRU combine + edge histogram (merged)
  k_gru_comb<<<NN * HH / 256 + EE / 256, 256, 0, stream>>>(gi, gh, tiles, h, hb, out_tiles,
                                                           ei, cnt);
  k_scan   <<<1, 256, 0, stream>>>(cnt, off, cur);
  k_scatter<<<EE / 256, 256, 0, stream>>>(ei, ea, cur, srcs, eas4);

  // GATv2 stack (fused score+aggregate per node, scalarized CSR loads)
  for (int l = 0; l < NLAYERS; l++){
    { dim3 g(NN / 64, 2);
      k_lin_gat<<<g, 256, 0, stream>>>(hb, Wlrb + l * 32768, blrc + l * 256, xlrb); }
    k_gat_agg<<<NN / 4, 256, 0, stream>>>(xlrb, off, srcs, eas4,
                                          gat_We + l * HH * EFEAT,
                                          gat_att + l * NHEADS * HDIM,
                                          gat_bias + l * HH, ln_g + l * HH, ln_b + l * HH,
                                          h, hb);
  }

  // global attention
  { dim3 g(NN / 64, 3);
    k_lin_qkv<<<g, 256, 0, stream>>>(hb, Winb, attn_bin, qb, kb, vt); }
  { dim3 gattn(NN / 64, NHEADS, KS);
    k_attn_flash<<<gattn, 256, 0, stream>>>(qb, kb, vt, pden, pacc); }
  k_attn_out<<<NN / 64, 256, 0, stream>>>(pden, pacc, Woutb, attn_bout, lng_g, lng_b,
                                          mask, h, hb, gsum, msum, mcnt);

  // edge heads + value head (merged, global_load_lds staging)
  k_edge_mfma<<<EE / 64 + 1, 256, 0, stream>>>(hb, eab, ei, wbE, mv_b1, fr_b1,
                                               mv_W2, mv_b2, fr_W2, fr_b2,
                                               gsum, msum, mcnt,
                                               vl_W1, vl_b1, vl_W2, vl_b2,
                                               out, out_val);
}

// Round 18
// 339.720 us; speedup vs baseline: 1.0124x; 1.0124x over previous
//
#include <hip/hip_runtime.h>
#include <math.h>

// StrategistGNN forward on MI355X. Round 18: revert round-17's global_load_lds
// staging (regressed); restore round-16 best-known configuration (340 us).
// N=4096, E=65536, H=128, 4x32 heads, L=4.

#define NN 4096
#define EE 65536
#define HH 128
#define NHEADS 4
#define HDIM 32
#define NLAYERS 4
#define NFEAT 16
#define GFEAT 8
#define EFEAT 4
#define KS 4     // key-splits for global attention
#define KPAD 296 // padded K stride (bf16) for edge-head GEMM
#define XSTR 136 // LDS row stride (bf16): 2-way bank aliasing only (free)
#define KSTR 40  // flash K-tile LDS row stride
#define VSTR 136 // flash V-tile LDS row stride (128 keys + 8 pad)
#define WPB 4541 // wprep blocks (ceil(1162497/256))

typedef short bf16x8 __attribute__((ext_vector_type(8)));
typedef float f32x4  __attribute__((ext_vector_type(4)));
union UB { uint4 u; bf16x8 v; };

__device__ __forceinline__ float gelu_f(float x){
  return 0.5f * x * (1.0f + erff(x * 0.7071067811865475f));
}
__device__ __forceinline__ float gelu_fast(float x){
  float u = x + 0.044715f * x * x * x;
  float t = __expf(-1.5957691216f * u);
  return x / (1.0f + t);
}
__device__ __forceinline__ float sigm_fast(float x){ return 1.0f / (1.0f + __expf(-x)); }
__device__ __forceinline__ float tanh_fast(float x){
  float t = __expf(-2.0f * fmaxf(x, -40.0f));
  return 1.0f - 2.0f * t / (1.0f + t);
}
__device__ __forceinline__ float softplus_f(float x){ return x > 20.0f ? x : log1pf(expf(x)); }
__device__ __forceinline__ unsigned short f2bf(float x){
  unsigned u = __float_as_uint(x);
  unsigned r = (u + 0x7FFFu + ((u >> 16) & 1u)) >> 16;
  return (unsigned short)r;
}
__device__ __forceinline__ float bf2f(unsigned short x){
  return __uint_as_float(((unsigned)x) << 16);
}
__device__ __forceinline__ unsigned pack2bf(float lo, float hi){
  unsigned a = (__float_as_uint(lo) + 0x8000u) >> 16;
  unsigned b = (__float_as_uint(hi) + 0x8000u) & 0xFFFF0000u;
  return a | b;
}

// ---------------- CSR build (scan + scatter) ----------------
__global__ void k_scan(const int* __restrict__ cnt, int* __restrict__ off, int* __restrict__ cur){
  __shared__ int part[256];
  int t = threadIdx.x;
  int local[16];
  int s = 0;
  #pragma unroll
  for (int i = 0; i < 16; i++){ local[i] = s; s += cnt[t * 16 + i]; }
  part[t] = s; __syncthreads();
  for (int o = 1; o < 256; o <<= 1){
    int v = (t >= o) ? part[t - o] : 0;
    __syncthreads();
    part[t] += v;
    __syncthreads();
  }
  int base = part[t] - s;
  #pragma unroll
  for (int i = 0; i < 16; i++){ int o = base + local[i]; off[t * 16 + i] = o; cur[t * 16 + i] = o; }
  if (t == 255) off[NN] = part[255];
}

__global__ void k_scatter(const int* __restrict__ ei, const float* __restrict__ ea,
                          int* __restrict__ cur,
                          int* __restrict__ srcs, float* __restrict__ eas4){
  int e = blockIdx.x * 256 + threadIdx.x;
  if (e < EE){
    int d = ei[EE + e];
    int p = atomicAdd(&cur[d], 1);
    srcs[p] = ei[e];
    float4 a = *(const float4*)(ea + e * 4);
    *(float4*)(eas4 + p * 4) = a;
  }
}

// ---------------- one-shot prep + node/global encoder (merged) ----------------
__global__ void k_wprep_enc(const float* __restrict__ Wih, const float* __restrict__ Whh,
                            const float* __restrict__ Wl, const float* __restrict__ Wr,
                            const float* __restrict__ Win, const float* __restrict__ Wout,
                            const float* __restrict__ tiles,
                            const float* __restrict__ bl, const float* __restrict__ br,
                            const float* __restrict__ ea,
                            const float* __restrict__ mvW1, const float* __restrict__ frW1,
                            unsigned short* __restrict__ wbuf, unsigned short* __restrict__ tilesb,
                            float* __restrict__ blrc,
                            unsigned short* __restrict__ wbE, unsigned short* __restrict__ eab,
                            int* __restrict__ cnt, float* __restrict__ gsum,
                            const float* __restrict__ x, const float* __restrict__ tf,
                            const float* __restrict__ neW, const float* __restrict__ neb,
                            const float* __restrict__ neg, const float* __restrict__ nebe,
                            const float* __restrict__ u, const float* __restrict__ geW,
                            const float* __restrict__ geb, const float* __restrict__ geg,
                            const float* __restrict__ gebe,
                            float* __restrict__ h, unsigned short* __restrict__ hb){
  int t = threadIdx.x;
  if (blockIdx.x < WPB){
    int i = blockIdx.x * 256 + t;
    if (i < 49152){ wbuf[i] = f2bf(Wih[i]); }
    else if (i < 98304){ int j = i - 49152; wbuf[49152 + j] = f2bf(Whh[j]); }
    else if (i < 229376){
      int j = i - 98304;
      int l = j >> 15, rem = j & 32767, m = rem >> 7, k = rem & 127;
      float v = (m < 128) ? Wl[l * 16384 + m * 128 + k] : Wr[l * 16384 + (m - 128) * 128 + k];
      wbuf[98304 + j] = f2bf(v);
    }
    else if (i < 278528){ int j = i - 229376; wbuf[229376 + j] = f2bf(Win[j]); }
    else if (i < 294912){ int j = i - 278528; wbuf[278528 + j] = f2bf(Wout[j]); }
    else if (i < 819200){ int j = i - 294912; tilesb[j] = f2bf(tiles[j]); }
    else if (i < 820224){
      int j = i - 819200;
      int l = j >> 8, m = j & 255;
      blrc[j] = (m < 128) ? bl[l * 128 + m] : br[l * 128 + m - 128];
    }
    else if (i < 896000){
      int j = i - 820224;
      int n = j / KPAD, k = j - n * KPAD;
      float v = 0.0f;
      if (k < 2 * HH + EFEAT) v = (n < HH) ? mvW1[n * (2 * HH + EFEAT) + k]
                                           : frW1[(n - HH) * (2 * HH + EFEAT) + k];
      wbE[j] = f2bf(v);
    }
    else if (i < 1158144){
      int j = i - 896000;
      eab[j] = f2bf(ea[j]);
    }
    else if (i < 1162240){ cnt[i - 1158144] = 0; }
    else if (i < 1162497){ gsum[i - 1162240] = 0.0f; }
    return;
  }
  __shared__ float red[256];
  __shared__ float xs[2][NFEAT + 1];
  __shared__ float us[GFEAT];
  int nb = blockIdx.x - WPB;
  int half = t >> 7, j = t & 127;
  int n = nb * 2 + half;
  if (j < NFEAT) xs[half][j] = x[n * NFEAT + j];
  if (j == NFEAT) xs[half][NFEAT] = tf[0];
  if (t < GFEAT) us[t] = u[t];
  __syncthreads();
  int rb = half * 128;
  float ua = geb[j];
  #pragma unroll
  for (int k = 0; k < GFEAT; k++) ua += us[k] * geW[j * GFEAT + k];
  red[rb + j] = ua; __syncthreads();
  #pragma unroll
  for (int s = 64; s > 0; s >>= 1){ if (j < s) red[rb + j] += red[rb + j + s]; __syncthreads(); }
  float umu = red[rb] * (1.0f / HH); __syncthreads();
  float ud = ua - umu;
  red[rb + j] = ud * ud; __syncthreads();
  #pragma unroll
  for (int s = 64; s > 0; s >>= 1){ if (j < s) red[rb + j] += red[rb + j + s]; __syncthreads(); }
  float uvar = red[rb] * (1.0f / HH); __syncthreads();
  float uej = gelu_f(ud * rsqrtf(uvar + 1e-5f) * geg[j] + gebe[j]);
  float acc = neb[j];
  #pragma unroll
  for (int k = 0; k < NFEAT + 1; k++) acc += xs[half][k] * neW[j * (NFEAT + 1) + k];
  red[rb + j] = acc; __syncthreads();
  #pragma unroll
  for (int s = 64; s > 0; s >>= 1){ if (j < s) red[rb + j] += red[rb + j + s]; __syncthreads(); }
  float mu = red[rb] * (1.0f / HH); __syncthreads();
  float d = acc - mu;
  red[rb + j] = d * d; __syncthreads();
  #pragma unroll
  for (int s = 64; s > 0; s >>= 1){ if (j < s) red[rb + j] += red[rb + j + s]; __syncthreads(); }
  float var = red[rb] * (1.0f / HH);
  float r = gelu_f(d * rsqrtf(var + 1e-5f) * neg[j] + nebe[j]) + uej;
  h[n * HH + j] = r;
  hb[n * HH + j] = f2bf(r);
}

// ---------------- shared GEMM core (64 rows x 128 cols, K=128) ----------------
__device__ __forceinline__ void gemm_core(const unsigned short* __restrict__ Xb, int n0,
                                          const unsigned short* __restrict__ Wb, int m0,
                                          unsigned short* Xs, f32x4 acc[8]){
  int t = threadIdx.x;
  #pragma unroll
  for (int k2 = 0; k2 < 4; k2++){
    int v = t + k2 * 256;
    int r = v >> 4, c8 = v & 15;
    *(uint4*)(Xs + r * XSTR + c8 * 8) = *(const uint4*)(Xb + (n0 + r) * 128 + c8 * 8);
  }
  __syncthreads();
  int ln = t & 63, w = t >> 6, lm = ln & 15, quad = ln >> 4;
  const unsigned short* abase = Xs + (16 * w + lm) * XSTR + quad * 8;
  const unsigned short* bbase = Wb + (m0 + lm) * 128 + quad * 8;
  UB af[4];
  #pragma unroll
  for (int ks = 0; ks < 4; ks++) af[ks].u = *(const uint4*)(abase + ks * 32);
  #pragma unroll
  for (int i = 0; i < 8; i++) acc[i] = (f32x4){0.f, 0.f, 0.f, 0.f};
  #pragma unroll
  for (int t2 = 0; t2 < 8; t2++){
    #pragma unroll
    for (int ks = 0; ks < 4; ks++){
      UB bu;
      bu.u = *(const uint4*)(bbase + t2 * 16 * 128 + ks * 32);
      acc[t2] = __builtin_amdgcn_mfma_f32_16x16x32_bf16(af[ks].v, bu.v, acc[t2], 0, 0, 0);
    }
  }
}

// GRU: both projections in one launch
__global__ __launch_bounds__(256) void k_gru_lin(const unsigned short* __restrict__ hb,
                                                 const unsigned short* __restrict__ tilesb,
                                                 const unsigned short* __restrict__ Wihb,
                                                 const unsigned short* __restrict__ Whhb,
                                                 const float* __restrict__ bih,
                                                 const float* __restrict__ bhh,
                                                 float* __restrict__ gi, float* __restrict__ gh){
  __shared__ __align__(16) unsigned short Xs[64 * XSTR];
  int z = blockIdx.z;
  const unsigned short* Xb = z ? tilesb : hb;
  const unsigned short* Wb = z ? Whhb : Wihb;
  const float* bias = z ? bhh : bih;
  float* Y = z ? gh : gi;
  int t = threadIdx.x;
  int n0 = blockIdx.x * 64, m0 = blockIdx.y * 128;
  f32x4 acc[8];
  gemm_core(Xb, n0, Wb, m0, Xs, acc);
  int ln = t & 63, w = t >> 6, lm = ln & 15, quad = ln >> 4;
  #pragma unroll
  for (int t2 = 0; t2 < 8; t2++){
    float bv = bias[m0 + t2 * 16 + lm];
    #pragma unroll
    for (int r = 0; r < 4; r++){
      Y[(n0 + 16 * w + quad * 4 + r) * 384 + m0 + t2 * 16 + lm] = acc[t2][r] + bv;
    }
  }
}

// GAT projection: bf16 out
__global__ __launch_bounds__(256) void k_lin_gat(const unsigned short* __restrict__ Xb,
                                                 const unsigned short* __restrict__ Wb,
                                                 const float* __restrict__ bias,
                                                 unsigned short* __restrict__ Y){
  __shared__ __align__(16) unsigned short Xs[64 * XSTR];
  int t = threadIdx.x;
  int n0 = blockIdx.x * 64, m0 = blockIdx.y * 128;
  f32x4 acc[8];
  gemm_core(Xb, n0, Wb, m0, Xs, acc);
  int ln = t & 63, w = t >> 6, lm = ln & 15, quad = ln >> 4;
  #pragma unroll
  for (int t2 = 0; t2 < 8; t2++){
    float bv = bias[m0 + t2 * 16 + lm];
    #pragma unroll
    for (int r = 0; r < 4; r++){
      Y[(n0 + 16 * w + quad * 4 + r) * 256 + m0 + t2 * 16 + lm] = f2bf(acc[t2][r] + bv);
    }
  }
}

// QKV projection with fused post
__global__ __launch_bounds__(256) void k_lin_qkv(const unsigned short* __restrict__ Xb,
                                                 const unsigned short* __restrict__ Wb,
                                                 const float* __restrict__ bias,
                                                 unsigned short* __restrict__ qb,
                                                 unsigned short* __restrict__ kb,
                                                 unsigned short* __restrict__ vt){
  __shared__ __align__(16) unsigned short Xs[64 * XSTR];
  int t = threadIdx.x;
  int n0 = blockIdx.x * 64, m0 = blockIdx.y * 128;
  f32x4 acc[8];
  gemm_core(Xb, n0, Wb, m0, Xs, acc);
  int ln = t & 63, w = t >> 6, lm = ln & 15, quad = ln >> 4;
  int nb = n0 + 16 * w + quad * 4;
  const float scale = 0.17677669529663687f;
  if (blockIdx.y == 0){
    #pragma unroll
    for (int t2 = 0; t2 < 8; t2++){
      int m = t2 * 16 + lm;
      float bv = bias[m];
      #pragma unroll
      for (int r = 0; r < 4; r++) qb[(nb + r) * HH + m] = f2bf(acc[t2][r] + bv);
    }
  } else if (blockIdx.y == 1){
    #pragma unroll
    for (int t2 = 0; t2 < 8; t2++){
      int m = t2 * 16 + lm;
      float bv = bias[128 + m];
      #pragma unroll
      for (int r = 0; r < 4; r++) kb[(nb + r) * HH + m] = f2bf((acc[t2][r] + bv) * scale);
    }
  } else {
    #pragma unroll
    for (int t2 = 0; t2 < 8; t2++){
      int m = t2 * 16 + lm;
      float bv = bias[256 + m];
      uint2 p;
      p.x = pack2bf(acc[t2][0] + bv, acc[t2][1] + bv);
      p.y = pack2bf(acc[t2][2] + bv, acc[t2][3] + bv);
      *(uint2*)(vt + m * NN + nb) = p;
    }
  }
}

// ---------------- GRU combine + edge histogram (merged) ----------------
__global__ void k_gru_comb(const float* __restrict__ gi, const float* __restrict__ gh,
                           const float* __restrict__ tiles, float* __restrict__ h,
                           unsigned short* __restrict__ hb, float* __restrict__ out_tiles,
                           const int* __restrict__ ei, int* __restrict__ cnt){
  int bid = blockIdx.x, t = threadIdx.x;
  if (bid >= NN * HH / 256){
    int e = (bid - NN * HH / 256) * 256 + t;
    if (e < EE) atomicAdd(&cnt[ei[EE + e]], 1);
    return;
  }
  int idx = bid * 256 + t;
  int n = idx >> 7, j = idx & 127;
  float ir = gi[n * 384 + j], iz = gi[n * 384 + 128 + j], inn = gi[n * 384 + 256 + j];
  float hr = gh[n * 384 + j], hz = gh[n * 384 + 128 + j], hn = gh[n * 384 + 256 + j];
  float r = sigm_fast(ir + hr), z = sigm_fast(iz + hz);
  float nn2 = tanh_fast(inn + r * hn);
  float ts = tiles[idx];
  float hnew = (1.0f - z) * nn2 + z * ts;
  h[idx] = hnew;
  hb[idx] = f2bf(hnew);
  out_tiles[idx] = hnew;
}

// ---------------- fused GAT score + aggregate + residual + LN ----------------
__global__ __launch_bounds__(256) void k_gat_agg(
    const unsigned short* __restrict__ xlrb,
    const int* __restrict__ off, const int* __restrict__ srcs,
    const float* __restrict__ eas4,
    const float* __restrict__ We, const float* __restrict__ att,
    const float* __restrict__ bias, const float* __restrict__ g,
    const float* __restrict__ b, float* __restrict__ h,
    unsigned short* __restrict__ hb){
  int t = threadIdx.x, w = t >> 6, j = t & 63;
  int n = blockIdx.x * 4 + w;
  int p0 = __builtin_amdgcn_readfirstlane(off[n]);
  int p1 = __builtin_amdgcn_readfirstlane(off[n + 1]);
  int c0 = 2 * j;
  float4 w0 = ((const float4*)We)[c0];
  float4 w1 = ((const float4*)We)[c0 + 1];
  float at0 = att[c0], at1 = att[c0 + 1];
  unsigned xr = *(const unsigned*)(xlrb + n * 256 + 128 + c0);
  float xr0 = bf2f((unsigned short)xr), xr1 = bf2f((unsigned short)(xr >> 16));
  float den = 0.f, a0 = 0.f, a1 = 0.f;
  int p = p0;
  for (; p + 4 <= p1; p += 4){
    int s0 = srcs[p], s1 = srcs[p + 1], s2 = srcs[p + 2], s3 = srcs[p + 3];
    unsigned x0 = *(const unsigned*)(xlrb + s0 * 256 + c0);
    unsigned x1 = *(const unsigned*)(xlrb + s1 * 256 + c0);
    unsigned x2 = *(const unsigned*)(xlrb + s2 * 256 + c0);
    unsigned x3 = *(const unsigned*)(xlrb + s3 * 256 + c0);
    float4 ev0 = *(const float4*)(eas4 + p * 4);
    float4 ev1 = *(const float4*)(eas4 + (p + 1) * 4);
    float4 ev2 = *(const float4*)(eas4 + (p + 2) * 4);
    float4 ev3 = *(const float4*)(eas4 + (p + 3) * 4);
    float x00 = bf2f((unsigned short)x0), x01 = bf2f((unsigned short)(x0 >> 16));
    float x10 = bf2f((unsigned short)x1), x11 = bf2f((unsigned short)(x1 >> 16));
    float x20 = bf2f((unsigned short)x2), x21 = bf2f((unsigned short)(x2 >> 16));
    float x30 = bf2f((unsigned short)x3), x31 = bf2f((unsigned short)(x3 >> 16));
    float vA0 = x00 + xr0 + ev0.x * w0.x + ev0.y * w0.y + ev0.z * w0.z + ev0.w * w0.w;
    float vA1 = x01 + xr1 + ev0.x * w1.x + ev0.y * w1.y + ev0.z * w1.z + ev0.w * w1.w;
    float vB0 = x10 + xr0 + ev1.x * w0.x + ev1.y * w0.y + ev1.z * w0.z + ev1.w * w0.w;
    float vB1 = x11 + xr1 + ev1.x * w1.x + ev1.y * w1.y + ev1.z * w1.z + ev1.w * w1.w;
    float vC0 = x20 + xr0 + ev2.x * w0.x + ev2.y * w0.y + ev2.z * w0.z + ev2.w * w0.w;
    float vC1 = x21 + xr1 + ev2.x * w1.x + ev2.y * w1.y + ev2.z * w1.z + ev2.w * w1.w;
    float vD0 = x30 + xr0 + ev3.x * w0.x + ev3.y * w0.y + ev3.z * w0.z + ev3.w * w0.w;
    float vD1 = x31 + xr1 + ev3.x * w1.x + ev3.y * w1.y + ev3.z * w1.z + ev3.w * w1.w;
    vA0 = vA0 > 0.f ? vA0 : 0.2f * vA0;  vA1 = vA1 > 0.f ? vA1 : 0.2f * vA1;
    vB0 = vB0 > 0.f ? vB0 : 0.2f * vB0;  vB1 = vB1 > 0.f ? vB1 : 0.2f * vB1;
    vC0 = vC0 > 0.f ? vC0 : 0.2f * vC0;  vC1 = vC1 > 0.f ? vC1 : 0.2f * vC1;
    vD0 = vD0 > 0.f ? vD0 : 0.2f * vD0;  vD1 = vD1 > 0.f ? vD1 : 0.2f * vD1;
    float sA = vA0 * at0 + vA1 * at1;
    float sB = vB0 * at0 + vB1 * at1;
    float sC = vC0 * at0 + vC1 * at1;
    float sD = vD0 * at0 + vD1 * at1;
    #pragma unroll
    for (int d = 1; d < 16; d <<= 1){
      sA += __shfl_xor(sA, d); sB += __shfl_xor(sB, d);
      sC += __shfl_xor(sC, d); sD += __shfl_xor(sD, d);
    }
    float eA = __expf(sA), eB = __expf(sB), eC = __expf(sC), eD = __expf(sD);
    den += (eA + eB) + (eC + eD);
    a0 += eA * x00 + eB * x10 + eC * x20 + eD * x30;
    a1 += eA * x01 + eB * x11 + eC * x21 + eD * x31;
  }
  for (; p < p1; p++){
    int s0 = srcs[p];
    float4 ev0 = *(const float4*)(eas4 + p * 4);
    unsigned x0 = *(const unsigned*)(xlrb + s0 * 256 + c0);
    float x00 = bf2f((unsigned short)x0), x01 = bf2f((unsigned short)(x0 >> 16));
    float vA0 = x00 + xr0 + ev0.x * w0.x + ev0.y * w0.y + ev0.z * w0.z + ev0.w * w0.w;
    float vA1 = x01 + xr1 + ev0.x * w1.x + ev0.y * w1.y + ev0.z * w1.z + ev0.w * w1.w;
    vA0 = vA0 > 0.f ? vA0 : 0.2f * vA0;  vA1 = vA1 > 0.f ? vA1 : 0.2f * vA1;
    float sA = vA0 * at0 + vA1 * at1;
    #pragma unroll
    for (int d = 1; d < 16; d <<= 1) sA += __shfl_xor(sA, d);
    float eA = __expf(sA);
    den += eA;
    a0 += eA * x00;
    a1 += eA * x01;
  }
  float dinv = 1.0f / (den + 1e-16f);
  float2 hv = *(const float2*)(h + n * HH + c0);
  float v0 = hv.x + a0 * dinv + bias[c0];
  float v1 = hv.y + a1 * dinv + bias[c0 + 1];
  float s = v0 + v1;
  #pragma unroll
  for (int d = 1; d < 64; d <<= 1) s += __shfl_xor(s, d);
  float mu = s * (1.0f / HH);
  float d0 = v0 - mu, d1 = v1 - mu;
  float q = d0 * d0 + d1 * d1;
  #pragma unroll
  for (int d = 1; d < 64; d <<= 1) q += __shfl_xor(q, d);
  float rstd = rsqrtf(q * (1.0f / HH) + 1e-5f);
  float o0 = d0 * rstd * g[c0] + b[c0];
  float o1 = d1 * rstd * g[c0 + 1] + b[c0 + 1];
  float2 ov; ov.x = o0; ov.y = o1;
  *(float2*)(h + n * HH + c0) = ov;
  unsigned pk = ((unsigned)f2bf(o0)) | (((unsigned)f2bf(o1)) << 16);
  *(unsigned*)(hb + n * HH + c0) = pk;
}

// ---------------- flash attention: 128-key double-buffered LDS chunks ----------------
__global__ __launch_bounds__(256, 4) void k_attn_flash(
    const unsigned short* __restrict__ qb, const unsigned short* __restrict__ kb,
    const unsigned short* __restrict__ vt,
    float* __restrict__ pden, float* __restrict__ pacc){
  __shared__ __align__(16) unsigned short Kls[2][128 * KSTR];
  __shared__ __align__(16) unsigned short Vls[2][32 * VSTR];
  int t = threadIdx.x, w = t >> 6, ln = t & 63;
  int c = ln & 15, qd = ln >> 4;
  int hh = blockIdx.y, ks = blockIdx.z;
  int q0 = blockIdx.x * 64 + w * 16;
  UB qf; qf.u = *(const uint4*)(qb + (q0 + c) * HH + hh * HDIM + qd * 8);
  f32x4 o0a = {0,0,0,0}, o1a = {0,0,0,0}, o0b = {0,0,0,0}, o1b = {0,0,0,0};
  float denp = 0.f;
  int srcA = c + ((qd & 1) << 5);
  int srcB = srcA + 16;
  bool hi = qd >= 2;
  int kk2 = t >> 1, kp2 = (t & 1) * 2;
  int vr2 = t >> 3, vc2 = (t & 7) * 2;
  const unsigned short* kg = kb + hh * HDIM + kp2 * 8;
  const unsigned short* vg = vt + (hh * HDIM + vr2) * NN + vc2 * 8;

  auto stage = [&](int buf, int k0){
    uint4 ka = *(const uint4*)(kg + (k0 + kk2) * HH);
    uint4 kb4 = *(const uint4*)(kg + (k0 + kk2) * HH + 8);
    uint4 va = *(const uint4*)(vg + k0);
    uint4 vb4 = *(const uint4*)(vg + k0 + 8);
    *(uint4*)(&Kls[buf][kk2 * KSTR + kp2 * 8]) = ka;
    *(uint4*)(&Kls[buf][kk2 * KSTR + kp2 * 8 + 8]) = kb4;
    *(uint4*)(&Vls[buf][vr2 * VSTR + vc2 * 8]) = va;
    *(uint4*)(&Vls[buf][vr2 * VSTR + vc2 * 8 + 8]) = vb4;
  };
  auto comp = [&](int buf, int hs, f32x4& O0, f32x4& O1){
    UB kf0, kf1, vf0, vf1, pt;
    kf0.u = *(const uint4*)(&Kls[buf][(hs * 32 + c) * KSTR + qd * 8]);
    kf1.u = *(const uint4*)(&Kls[buf][(hs * 32 + 16 + c) * KSTR + qd * 8]);
    vf0.u = *(const uint4*)(&Vls[buf][c * VSTR + hs * 32 + qd * 8]);
    vf1.u = *(const uint4*)(&Vls[buf][(16 + c) * VSTR + hs * 32 + qd * 8]);
    f32x4 s0 = {0,0,0,0}, s1 = {0,0,0,0};
    s0 = __builtin_amdgcn_mfma_f32_16x16x32_bf16(kf0.v, qf.v, s0, 0, 0, 0);
    s1 = __builtin_amdgcn_mfma_f32_16x16x32_bf16(kf1.v, qf.v, s1, 0, 0, 0);
    float e00 = __expf(s0[0]), e01 = __expf(s0[1]), e02 = __expf(s0[2]), e03 = __expf(s0[3]);
    float e10 = __expf(s1[0]), e11 = __expf(s1[1]), e12 = __expf(s1[2]), e13 = __expf(s1[3]);
    denp += (e00 + e01) + (e02 + e03) + (e10 + e11) + (e12 + e13);
    int p00 = (int)pack2bf(e00, e01), p01 = (int)pack2bf(e02, e03);
    int p10 = (int)pack2bf(e10, e11), p11 = (int)pack2bf(e12, e13);
    int a00 = __shfl(p00, srcA), a01 = __shfl(p01, srcA);
    int b00 = __shfl(p00, srcB), b01 = __shfl(p01, srcB);
    int a10 = __shfl(p10, srcA), a11 = __shfl(p11, srcA);
    int b10 = __shfl(p10, srcB), b11 = __shfl(p11, srcB);
    pt.u.x = (unsigned)(hi ? a10 : a00);
    pt.u.y = (unsigned)(hi ? a11 : a01);
    pt.u.z = (unsigned)(hi ? b10 : b00);
    pt.u.w = (unsigned)(hi ? b11 : b01);
    O0 = __builtin_amdgcn_mfma_f32_16x16x32_bf16(vf0.v, pt.v, O0, 0, 0, 0);
    O1 = __builtin_amdgcn_mfma_f32_16x16x32_bf16(vf1.v, pt.v, O1, 0, 0, 0);
  };

  const int kbeg = ks * (NN / KS);
  const int NIT = (NN / KS) / 128;   // 8
  stage(0, kbeg);
  __syncthreads();
  for (int it = 0; it < NIT; it++){
    int buf = it & 1;
    if (it + 1 < NIT){
      int kn = kbeg + (it + 1) * 128;
      uint4 ka = *(const uint4*)(kg + (kn + kk2) * HH);
      uint4 kb4 = *(const uint4*)(kg + (kn + kk2) * HH + 8);
      uint4 va = *(const uint4*)(vg + kn);
      uint4 vb4 = *(const uint4*)(vg + kn + 8);
      comp(buf, 0, o0a, o1a);
      comp(buf, 1, o0b, o1b);
      comp(buf, 2, o0a, o1a);
      comp(buf, 3, o0b, o1b);
      *(uint4*)(&Kls[buf ^ 1][kk2 * KSTR + kp2 * 8]) = ka;
      *(uint4*)(&Kls[buf ^ 1][kk2 * KSTR + kp2 * 8 + 8]) = kb4;
      *(uint4*)(&Vls[buf ^ 1][vr2 * VSTR + vc2 * 8]) = va;
      *(uint4*)(&Vls[buf ^ 1][vr2 * VSTR + vc2 * 8 + 8]) = vb4;
    } else {
      comp(buf, 0, o0a, o1a);
      comp(buf, 1, o0b, o1b);
      comp(buf, 2, o0a, o1a);
      comp(buf, 3, o0b, o1b);
    }
    __syncthreads();
  }

  f32x4 o0 = o0a + o0b, o1 = o1a + o1b;
  denp += __shfl_xor(denp, 16);
  denp += __shfl_xor(denp, 32);
  int pi = ((q0 + c) * NHEADS + hh) * KS + ks;
  if (qd == 0) pden[pi] = denp;
  #pragma unroll
  for (int r = 0; r < 4; r++){
    pacc[pi * HDIM + qd * 4 + r]      = o0[r];
    pacc[pi * HDIM + 16 + qd * 4 + r] = o1[r];
  }
}

// fused: combine partials -> MFMA proj -> residual+LN -> h,hb + value-head pooling
__global__ __launch_bounds__(256) void k_attn_out(
    const float* __restrict__ pden, const float* __restrict__ pacc,
    const unsigned short* __restrict__ Wb, const float* __restrict__ bout,
    const float* __restrict__ g, const float* __restrict__ b,
    const unsigned char* __restrict__ mask,
    float* __restrict__ h, unsigned short* __restrict__ hb,
    float* __restrict__ gsum, float* __restrict__ msum, float* __restrict__ mcnt){
  __shared__ __align__(16) unsigned short Xs[64 * XSTR];
  __shared__ float colg[128], colm[128], colc;
  int t = threadIdx.x;
  int n0 = blockIdx.x * 64;
  if (t < 128){ colg[t] = 0.f; colm[t] = 0.f; }
  if (t == 128) colc = 0.f;
  for (int idx = t; idx < 64 * 128; idx += 256){
    int r = idx >> 7, j = idx & 127;
    int n = n0 + r, hh = j >> 5, d = j & 31;
    float ds = 0.f, as = 0.f;
    #pragma unroll
    for (int ks2 = 0; ks2 < KS; ks2++){
      int pi = (n * NHEADS + hh) * KS + ks2;
      ds += pden[pi];
      as += pacc[pi * HDIM + d];
    }
    Xs[r * XSTR + j] = f2bf(as / ds);
  }
  __syncthreads();
  int ln = t & 63, w = t >> 6, lm = ln & 15, quad = ln >> 4;
  const unsigned short* abase = Xs + (16 * w + lm) * XSTR + quad * 8;
  const unsigned short* bbase = Wb + lm * 128 + quad * 8;
  UB af[4];
  #pragma unroll
  for (int ks2 = 0; ks2 < 4; ks2++) af[ks2].u = *(const uint4*)(abase + ks2 * 32);
  f32x4 acc[8];
  #pragma unroll
  for (int i = 0; i < 8; i++) acc[i] = (f32x4){0.f, 0.f, 0.f, 0.f};
  #pragma unroll
  for (int t2 = 0; t2 < 8; t2++){
    #pragma unroll
    for (int ks2 = 0; ks2 < 4; ks2++){
      UB bu;
      bu.u = *(const uint4*)(bbase + t2 * 16 * 128 + ks2 * 32);
      acc[t2] = __builtin_amdgcn_mfma_f32_16x16x32_bf16(af[ks2].v, bu.v, acc[t2], 0, 0, 0);
    }
  }
  int nb = n0 + 16 * w + quad * 4;
  float val[8][4];
  #pragma unroll
  for (int t2 = 0; t2 < 8; t2++){
    int m = t2 * 16 + lm;
    float bv = bout[m];
    #pragma unroll
    for (int r = 0; r < 4; r++)
      val[t2][r] = acc[t2][r] + bv + h[(nb + r) * HH + m];
  }
  float mu[4], rs[4];
  #pragma unroll
  for (int r = 0; r < 4; r++){
    float s = 0.f;
    #pragma unroll
    for (int t2 = 0; t2 < 8; t2++) s += val[t2][r];
    s += __shfl_xor(s, 1); s += __shfl_xor(s, 2);
    s += __shfl_xor(s, 4); s += __shfl_xor(s, 8);
    mu[r] = s * (1.0f / HH);
  }
  #pragma unroll
  for (int r = 0; r < 4; r++){
    float s = 0.f;
    #pragma unroll
    for (int t2 = 0; t2 < 8; t2++){ float d2 = val[t2][r] - mu[r]; s += d2 * d2; }
    s += __shfl_xor(s, 1); s += __shfl_xor(s, 2);
    s += __shfl_xor(s, 4); s += __shfl_xor(s, 8);
    rs[r] = rsqrtf(s * (1.0f / HH) + 1e-5f);
  }
  uchar4 mk = *(const uchar4*)(mask + nb);
  float mkf[4] = { mk.x ? 1.f : 0.f, mk.y ? 1.f : 0.f, mk.z ? 1.f : 0.f, mk.w ? 1.f : 0.f };
  #pragma unroll
  for (int t2 = 0; t2 < 8; t2++){
    int m = t2 * 16 + lm;
    float gm = g[m], bm = b[m];
    float sg = 0.f, sm = 0.f;
    #pragma unroll
    for (int r = 0; r < 4; r++){
      float o = (val[t2][r] - mu[r]) * rs[r] * gm + bm;
      h[(nb + r) * HH + m] = o;
      hb[(nb + r) * HH + m] = f2bf(o);
      sg += o;
      sm += mkf[r] * o;
    }
    sg += __shfl_xor(sg, 16); sg += __shfl_xor(sg, 32);
    sm += __shfl_xor(sm, 16); sm += __shfl_xor(sm, 32);
    if (quad == 0){
      atomicAdd(&colg[m], sg);
      atomicAdd(&colm[m], sm);
    }
  }
  if (lm == 0){
    float c = mkf[0] + mkf[1] + mkf[2] + mkf[3];
    atomicAdd(&colc, c);
  }
  __syncthreads();
  if (t < 128){
    atomicAdd(&gsum[t], colg[t]);
    atomicAdd(&msum[t], colm[t]);
  }
  if (t == 128) atomicAdd(mcnt, colc);
}

// ---------------- edge heads via MFMA + value head (merged) ----------------
__global__ __launch_bounds__(256, 4) void k_edge_mfma(
    const unsigned short* __restrict__ hb, const unsigned short* __restrict__ eab,
    const int* __restrict__ ei, const unsigned short* __restrict__ wb,
    const float* __restrict__ mvb1, const float* __restrict__ frb1,
    const float* __restrict__ mvW2, const float* __restrict__ mvb2,
    const float* __restrict__ frW2, const float* __restrict__ frb2,
    const float* __restrict__ gsum, const float* __restrict__ msum,
    const float* __restrict__ mcnt,
    const float* __restrict__ vlW1, const float* __restrict__ vlb1,
    const float* __restrict__ vlW2, const float* __restrict__ vlb2,
    float* __restrict__ out, float* __restrict__ out_val){
  __shared__ __align__(16) unsigned short As[64 * KPAD];
  __shared__ float am[64], a0[64], a1[64];
  __shared__ float red[128];
  __shared__ float vin[256];
  int t = threadIdx.x;
  if (blockIdx.x == EE / 64){
    int j = t & 127;
    if (t < 128){
      float gp = gsum[j] * (1.0f / NN);
      float as2 = msum[j] * (1.0f / NN);
      float ac = fmaxf(mcnt[0] * (1.0f / NN), 1e-6f);
      vin[j] = gp; vin[HH + j] = as2 / ac;
    }
    __syncthreads();
    float hv = 0.f;
    if (t < 128){
      float acc2 = vlb1[j];
      const float* wv = &vlW1[j * 256];
      #pragma unroll 4
      for (int k = 0; k < 256; k++) acc2 += vin[k] * wv[k];
      hv = gelu_f(acc2) * vlW2[j];
    }
    if (t < 128) red[j] = hv;
    __syncthreads();
    #pragma unroll
    for (int s = 64; s > 0; s >>= 1){
      if (t < s) red[t] += red[t + s];
      __syncthreads();
    }
    if (t == 0) out_val[0] = red[0] + vlb2[0];
    return;
  }
  int e0 = blockIdx.x * 64;
  if (t < 64){ am[t] = 0.f; a0[t] = 0.f; a1[t] = 0.f; }
  {
    int el = t >> 2, p = t & 3;
    int e = e0 + el;
    int node = (p < 2) ? ei[e] : ei[EE + e];
    int half = p & 1;
    const uint4* srcp = (const uint4*)(hb + node * HH + half * 64);
    uint4* dstp = (uint4*)(As + el * KPAD + (p >> 1) * 128 + half * 64);
    #pragma unroll
    for (int i = 0; i < 8; i++) dstp[i] = srcp[i];
    if (p == 0){
      unsigned short* tail = As + el * KPAD + 256;
      tail[0] = eab[e * 4];     tail[1] = eab[e * 4 + 1];
      tail[2] = eab[e * 4 + 2]; tail[3] = eab[e * 4 + 3];
      #pragma unroll
      for (int i = 4; i < KPAD - 256; i++) tail[i] = 0;
    }
  }
  int ln = t & 63, w = t >> 6, lm = ln & 15, quad = ln >> 4;
  const unsigned short* bbase = wb + (w * 64 + lm) * KPAD + quad * 8;
  f32x4 acc[4][4];
  #pragma unroll
  for (int rt = 0; rt < 4; rt++)
    #pragma unroll
    for (int t2 = 0; t2 < 4; t2++) acc[rt][t2] = (f32x4){0.f, 0.f, 0.f, 0.f};
  __syncthreads();
  #pragma unroll
  for (int ks = 0; ks < 9; ks++){
    UB bf[4], af[4];
    #pragma unroll
    for (int t2 = 0; t2 < 4; t2++) bf[t2].u = *(const uint4*)(bbase + t2 * 16 * KPAD + ks * 32);
    #pragma unroll
    for (int rt = 0; rt < 4; rt++) af[rt].u = *(const uint4*)(As + (16 * rt + lm) * KPAD + quad * 8 + ks * 32);
    #pragma unroll
    for (int rt = 0; rt < 4; rt++)
      #pragma unroll
      for (int t2 = 0; t2 < 4; t2++)
        acc[rt][t2] = __builtin_amdgcn_mfma_f32_16x16x32_bf16(af[rt].v, bf[t2].v, acc[rt][t2], 0, 0, 0);
  }
  if (w < 2){
    #pragma unroll
    for (int rt = 0; rt < 4; rt++){
      #pragma unroll
      for (int r = 0; r < 4; r++){
        float s = 0.f;
        #pragma unroll
        for (int t2 = 0; t2 < 4; t2++){
          int n = w * 64 + t2 * 16 + lm;
          s += gelu_fast(acc[rt][t2][r] + mvb1[n]) * mvW2[n];
        }
        #pragma unroll
        for (int d = 1; d < 16; d <<= 1) s += __shfl_xor(s, d);
        if (lm == 0) atomicAdd(&am[16 * rt + 4 * quad + r], s);
      }
    }
  } else {
    #pragma unroll
    for (int rt = 0; rt < 4; rt++){
      #pragma unroll
      for (int r = 0; r < 4; r++){
        float s0 = 0.f, s1 = 0.f;
        #pragma unroll
        for (int t2 = 0; t2 < 4; t2++){
          int n = (w - 2) * 64 + t2 * 16 + lm;
          float g = gelu_fast(acc[rt][t2][r] + frb1[n]);
          s0 += g * frW2[n];
          s1 += g * frW2[128 + n];
        }
        #pragma unroll
        for (int d = 1; d < 16; d <<= 1){ s0 += __shfl_xor(s0, d); s1 += __shfl_xor(s1, d); }
        if (lm == 0){
          atomicAdd(&a0[16 * rt + 4 * quad + r], s0);
          atomicAdd(&a1[16 * rt + 4 * quad + r], s1);
        }
      }
    }
  }
  __syncthreads();
  if (t < 64){
    int e = e0 + t;
    out[e]          = am[t] + mvb2[0];
    out[EE + e]     = softplus_f(a0[t] + frb2[0]) + 1e-4f;
    out[2 * EE + e] = softplus_f(a1[t] + frb2[1]) + 1e-4f;
  }
}

extern "C" void kernel_launch(void* const* d_in, const int* in_sizes, int n_in,
                              void* d_out, int out_size, void* d_ws, size_t ws_size,
                              hipStream_t stream){
  (void)in_sizes; (void)n_in; (void)out_size; (void)ws_size;
  const float* x        = (const float*)d_in[0];
  const int*   ei       = (const int*)d_in[1];
  const float* ea       = (const float*)d_in[2];
  const float* u        = (const float*)d_in[3];
  const unsigned char* mask = (const unsigned char*)d_in[4];
  const float* tiles    = (const float*)d_in[5];
  const float* tf       = (const float*)d_in[7];
  const float* ne_W  = (const float*)d_in[8];
  const float* ne_b  = (const float*)d_in[9];
  const float* ne_g  = (const float*)d_in[10];
  const float* ne_be = (const float*)d_in[11];
  const float* ge_W  = (const float*)d_in[12];
  const float* ge_b  = (const float*)d_in[13];
  const float* ge_g  = (const float*)d_in[14];
  const float* ge_be = (const float*)d_in[15];
  const float* gru_Wih = (const float*)d_in[16];
  const float* gru_bih = (const float*)d_in[17];
  const float* gru_Whh = (const float*)d_in[18];
  const float* gru_bhh = (const float*)d_in[19];
  const float* gat_Wl  = (const float*)d_in[20];
  const float* gat_bl  = (const float*)d_in[21];
  const float* gat_Wr  = (const float*)d_in[22];
  const float* gat_br  = (const float*)d_in[23];
  const float* gat_We  = (const float*)d_in[24];
  const float* gat_att = (const float*)d_in[25];
  const float* gat_bias= (const float*)d_in[26];
  const float* ln_g    = (const float*)d_in[27];
  const float* ln_b    = (const float*)d_in[28];
  const float* attn_Win = (const float*)d_in[29];
  const float* attn_bin = (const float*)d_in[30];
  const float* attn_Wout= (const float*)d_in[31];
  const float* attn_bout= (const float*)d_in[32];
  const float* lng_g    = (const float*)d_in[33];
  const float* lng_b    = (const float*)d_in[34];
  const float* mv_W1 = (const float*)d_in[35];
  const float* mv_b1 = (const float*)d_in[36];
  const float* mv_W2 = (const float*)d_in[37];
  const float* mv_b2 = (const float*)d_in[38];
  const float* fr_W1 = (const float*)d_in[39];
  const float* fr_b1 = (const float*)d_in[40];
  const float* fr_W2 = (const float*)d_in[41];
  const float* fr_b2 = (const float*)d_in[42];
  const float* vl_W1 = (const float*)d_in[43];
  const float* vl_b1 = (const float*)d_in[44];
  const float* vl_W2 = (const float*)d_in[45];
  const float* vl_b2 = (const float*)d_in[46];

  // ---- workspace layout (f32 elem offsets) ----
  float* ws = (float*)d_ws;
  float* h      = ws;                         // 524288
  float* xlr    = ws + 524288;                // reused: GAT xlrb, attn qb/kb/vt
  unsigned short* hb     = (unsigned short*)(ws + 1572864);
  unsigned short* tilesb = (unsigned short*)(ws + 1835008);
  unsigned short* wbuf   = (unsigned short*)(ws + 2097152);
  unsigned short* Wihb  = wbuf;
  unsigned short* Whhb  = wbuf + 49152;
  unsigned short* Wlrb  = wbuf + 98304;
  unsigned short* Winb  = wbuf + 229376;
  unsigned short* Woutb = wbuf + 278528;
  float* blrc   = ws + 2244608;
  float* gsum   = ws + 2245760;
  float* msum   = ws + 2245888;
  float* mcnt   = ws + 2246016;
  int*   cnt    = (int*)(ws + 2246032);
  int*   off    = cnt + NN;
  int*   cur    = off + NN + 1;
  unsigned short* eab = (unsigned short*)(ws + 2323904);
  unsigned short* wbE = (unsigned short*)(ws + 2454976);
  float* S      = ws + 2492864;               // 3145728 scratch (multi-phase)
  float* gi = S;
  float* gh = S + 1572864;
  float* eas4 = S;                                        // EE*4 f32 CSR-slot attrs
  int*   srcs = (int*)(S + 262144);                       // EE
  unsigned short* xlrb = (unsigned short*)xlr;            // NN*256 bf16
  unsigned short* qb = (unsigned short*)xlr;
  unsigned short* kb = (unsigned short*)(xlr + 262144);
  unsigned short* vt = (unsigned short*)(xlr + 524288 + 16384);
  float* pacc = S + 327680;                               // NN*4*KS*32 f32
  float* pden = S + 327680 + 2097152;                     // NN*4*KS

  float* out       = (float*)d_out;
  float* out_val   = out + 3 * EE;
  float* out_tiles = out + 3 * EE + 1;

  // one-shot bf16 prep + zero-init + node/global encoder (merged)
  k_wprep_enc<<<WPB + NN / 2, 256, 0, stream>>>(gru_Wih, gru_Whh, gat_Wl, gat_Wr,
                                                attn_Win, attn_Wout, tiles,
                                                gat_bl, gat_br, ea, mv_W1, fr_W1,
                                                wbuf, tilesb, blrc, wbE, eab,
                                                cnt, gsum,
                                                x, tf, ne_W, ne_b, ne_g, ne_be,
                                                u, ge_W, ge_b, ge_g, ge_be, h, hb);

  // GRU via MFMA (both projections in one launch)
  { dim3 g(NN / 64, 3, 2);
    k_gru_lin<<<g, 256, 0, stream>>>(hb, tilesb, Wihb, Whhb, gru_bih, gru_bhh, gi, gh); }
  // GRU combine + edge histogram (merged)
  k_gru_comb<<<NN * HH / 256 + EE / 256, 256, 0, stream>>>(gi, gh, tiles, h, hb, out_tiles,
                                                           ei, cnt);
  k_scan   <<<1, 256, 0, stream>>>(cnt, off, cur);
  k_scatter<<<EE / 256, 256, 0, stream>>>(ei, ea, cur, srcs, eas4);

  // GATv2 stack (fused score+aggregate per node, scalarized CSR loads)
  for (int l = 0; l < NLAYERS; l++){
    { dim3 g(NN / 64, 2);
      k_lin_gat<<<g, 256, 0, stream>>>(hb, Wlrb + l * 32768, blrc + l * 256, xlrb); }
    k_gat_agg<<<NN / 4, 256, 0, stream>>>(xlrb, off, srcs, eas4,
                                          gat_We + l * HH * EFEAT,
                                          gat_att + l * NHEADS * HDIM,
                                          gat_bias + l * HH, ln_g + l * HH, ln_b + l * HH,
                                          h, hb);
  }

  // global attention
  { dim3 g(NN / 64, 3);
    k_lin_qkv<<<g, 256, 0, stream>>>(hb, Winb, attn_bin, qb, kb, vt); }
  { dim3 gattn(NN / 64, NHEADS, KS);
    k_attn_flash<<<gattn, 256, 0, stream>>>(qb, kb, vt, pden, pacc); }
  k_attn_out<<<NN / 64, 256, 0, stream>>>(pden, pacc, Woutb, attn_bout, lng_g, lng_b,
                                          mask, h, hb, gsum, msum, mcnt);

  // edge heads + value head (merged)
  k_edge_mfma<<<EE / 64 + 1, 256, 0, stream>>>(hb, eab, ei, wbE, mv_b1, fr_b1,
                                               mv_W2, mv_b2, fr_W2, fr_b2,
                                               gsum, msum, mcnt,
                                               vl_W1, vl_b1, vl_W2, vl_b2,
                                               out, out_val);
}